// Round 1
// baseline (35701.364 us; speedup 1.0000x reference)
//
#include <hip/hip_runtime.h>
#include <hip/hip_bf16.h>
#include <math.h>

#define NB    256     // batch
#define CDD   5
#define HIS   50
#define NITEMS (CDD + HIS)
#define TT    20      // tokens per title
#define DD    300     // embedding dim
#define NH    16      // heads
#define VDIM  16      // per-head value dim
#define RP    256     // NH*VDIM
#define QDIM  200
#define SCALEF 0.057735026918962584f   // 1/sqrt(300)

#define DP    301     // padded DD (odd -> conflict-free strided col reads)
#define FP2   257     // padded RP
#define CHW   129     // padded 128-chunk

// ---------------------------------------------------------------------------
// Word-level encoder: one block per news item (candidate or clicked).
// Fused: embed-gather -> per-head MHSA -> additive pooling -> repr[256]
// ---------------------------------------------------------------------------
__global__ __launch_bounds__(512)
void word_encoder_kernel(const int* __restrict__ cddT, const int* __restrict__ hisT,
                         const float* __restrict__ E,
                         const float* __restrict__ Wq, const float* __restrict__ Wv,
                         const float* __restrict__ Wk, const float* __restrict__ bk,
                         const float* __restrict__ qv,
                         float* __restrict__ cddR, float* __restrict__ hisR)
{
    __shared__ float Xs[TT][DP];      // 24,080 B  token embeddings
    __shared__ float Qh[TT][DP];      // 24,080 B  per-head Q (reused as Keys)
    __shared__ float XV[TT][RP];      // 20,480 B  X*Wv all heads
    __shared__ float Vl[TT][RP];      // 20,480 B  attention values (concat heads)
    __shared__ float Sm[TT][TT + 1];  //  1,680 B  scores/softmax
    __shared__ float wr[TT];
    __shared__ int   toks[TT];

    const int tid = threadIdx.x;
    const int blk = blockIdx.x;
    const int b   = blk / NITEMS;
    const int it  = blk - b * NITEMS;
    const int*  tp;
    float*      op;
    if (it < CDD) { tp = cddT + (b * CDD + it) * TT; op = cddR + (b * CDD + it) * RP; }
    else { const int j = it - CDD; tp = hisT + (b * HIS + j) * TT; op = hisR + (b * HIS + j) * RP; }

    if (tid < TT) toks[tid] = tp[tid];
    __syncthreads();
    for (int i = tid; i < TT * DD; i += 512) {
        const int s = i / DD, f = i - s * DD;
        Xs[s][f] = E[toks[s] * DD + f];
    }
    __syncthreads();

    // XV[s][h*16+v] = sum_f Xs[s][f] * Wv[h][f][v]
    {
        const int sg = tid >> 7, ht = tid & 127;
        const int s0 = sg * 5;
        const int h0 = ht >> 4, v0 = ht & 15;
        const int h1 = (ht + 128) >> 4;
        const float* wp0 = Wv + h0 * (DD * VDIM) + v0;
        const float* wp1 = Wv + h1 * (DD * VDIM) + v0;
        float acc[5][2] = {};
        for (int f = 0; f < DD; ++f) {
            const float w0 = wp0[f * VDIM], w1 = wp1[f * VDIM];
            #pragma unroll
            for (int i = 0; i < 5; ++i) {
                const float x = Xs[s0 + i][f];
                acc[i][0] += x * w0;
                acc[i][1] += x * w1;
            }
        }
        #pragma unroll
        for (int i = 0; i < 5; ++i) {
            XV[s0 + i][ht]       = acc[i][0];
            XV[s0 + i][ht + 128] = acc[i][1];
        }
    }
    // first read of XV is after several syncs inside the head loop

    for (int h = 0; h < NH; ++h) {
        __syncthreads();   // Qh / Sm safe to overwrite
        // Qh = Xs * Wq[h]   (4 s-groups x 128 e-threads, acc[5][3] in regs)
        {
            const int sg = tid >> 7, et = tid & 127;
            const int s0 = sg * 5;
            const bool has3 = (et + 256) < DD;     // et < 44
            const float* wq = Wq + h * (DD * DD) + et;
            float acc[5][3] = {};
            for (int f = 0; f < DD; ++f) {
                const float* wp = wq + f * DD;
                const float w0 = wp[0];
                const float w1 = wp[128];
                const float w2 = has3 ? wp[256] : 0.f;
                #pragma unroll
                for (int i = 0; i < 5; ++i) {
                    const float x = Xs[s0 + i][f];
                    acc[i][0] += x * w0;
                    acc[i][1] += x * w1;
                    acc[i][2] += x * w2;
                }
            }
            #pragma unroll
            for (int i = 0; i < 5; ++i) {
                Qh[s0 + i][et]       = acc[i][0];
                Qh[s0 + i][et + 128] = acc[i][1];
                if (has3) Qh[s0 + i][et + 256] = acc[i][2];
            }
        }
        __syncthreads();
        // scores = Qh * Xs^T * SCALE
        for (int o = tid; o < TT * TT; o += 512) {
            const int s = o / TT, t = o - s * TT;
            float acc = 0.f;
            for (int e = 0; e < DD; ++e) acc += Qh[s][e] * Xs[t][e];
            Sm[s][t] = acc * SCALEF;
        }
        __syncthreads();
        if (tid < TT) {
            const int s = tid;
            float m = -1e30f;
            for (int t = 0; t < TT; ++t) m = fmaxf(m, Sm[s][t]);
            float sum = 0.f;
            for (int t = 0; t < TT; ++t) { const float e = __expf(Sm[s][t] - m); Sm[s][t] = e; sum += e; }
            const float inv = 1.f / sum;
            for (int t = 0; t < TT; ++t) Sm[s][t] *= inv;
        }
        __syncthreads();
        // Vl[:, h*16 .. h*16+15] = Sm * XV[:, h*16 .. ]
        for (int o = tid; o < TT * VDIM; o += 512) {
            const int s = o >> 4, v = o & 15;
            float acc = 0.f;
            for (int t = 0; t < TT; ++t) acc += Sm[s][t] * XV[t][h * VDIM + v];
            Vl[s][h * VDIM + v] = acc;
        }
    }
    __syncthreads();

    // Keys (reuse Qh): key[s][q] = tanh(bk[q] + sum_r Vl[s][r]*Wk[r][q])
    {
        const int sg = tid >> 7, qt = tid & 127;
        const int s0 = sg * 5;
        const bool has2 = (qt + 128) < QDIM;   // qt < 72
        float acc[5][2];
        const float b0 = bk[qt];
        const float b1 = has2 ? bk[qt + 128] : 0.f;
        #pragma unroll
        for (int i = 0; i < 5; ++i) { acc[i][0] = b0; acc[i][1] = b1; }
        for (int r = 0; r < RP; ++r) {
            const float* wp = Wk + r * QDIM + qt;
            const float w0 = wp[0];
            const float w1 = has2 ? wp[128] : 0.f;
            #pragma unroll
            for (int i = 0; i < 5; ++i) {
                const float x = Vl[s0 + i][r];
                acc[i][0] += x * w0;
                acc[i][1] += x * w1;
            }
        }
        #pragma unroll
        for (int i = 0; i < 5; ++i) {
            Qh[s0 + i][qt] = tanhf(acc[i][0]);
            if (has2) Qh[s0 + i][qt + 128] = tanhf(acc[i][1]);
        }
    }
    __syncthreads();
    if (tid < TT) {
        float acc = 0.f;
        for (int q = 0; q < QDIM; ++q) acc += qv[q] * Qh[tid][q];
        wr[tid] = acc * SCALEF;
    }
    __syncthreads();
    if (tid == 0) {
        float m = -1e30f;
        for (int s = 0; s < TT; ++s) m = fmaxf(m, wr[s]);
        float sum = 0.f;
        for (int s = 0; s < TT; ++s) { const float e = __expf(wr[s] - m); wr[s] = e; sum += e; }
        const float inv = 1.f / sum;
        for (int s = 0; s < TT; ++s) wr[s] *= inv;
    }
    __syncthreads();
    for (int r = tid; r < RP; r += 512) {
        float acc = 0.f;
        #pragma unroll
        for (int s = 0; s < TT; ++s) acc += wr[s] * Vl[s][r];
        op[r] = acc;
    }
}

// ---------------------------------------------------------------------------
// User encoder: news-level MHSA over 50 history reprs + additive pooling.
// One block per batch element.
// ---------------------------------------------------------------------------
__global__ __launch_bounds__(512)
void user_encoder_kernel(const float* __restrict__ hisR,
                         const float* __restrict__ Wq, const float* __restrict__ Wv,
                         const float* __restrict__ Wk, const float* __restrict__ bk,
                         const float* __restrict__ qv,
                         float* __restrict__ userR)
{
    __shared__ float Xs[HIS + 1][FP2];    // 52,428 B (+1 pad row for reg-tile tails)
    __shared__ float Vl[HIS][FP2];        // 51,400 B
    __shared__ float Qc[HIS + 1][CHW];    // 26,316 B  Q e-chunk
    __shared__ float Sm[HIS][HIS + 2];    // 10,400 B
    __shared__ float XVh[HIS][VDIM + 1];  //  3,400 B
    __shared__ float wr[HIS];

    const int tid = threadIdx.x;
    const int b = blockIdx.x;
    const float* xp = hisR + b * (HIS * RP);
    for (int i = tid; i < HIS * RP; i += 512) {
        const int s = i >> 8, f = i & 255;
        Xs[s][f] = xp[i];
    }
    __syncthreads();

    for (int h = 0; h < NH; ++h) {
        for (int chunk = 0; chunk < 2; ++chunk) {
            __syncthreads();                 // Qc/Sm reuse safety
            const int e0 = chunk * 128;
            {   // Qc[s][e'] = sum_f Xs[s][f] * Wq[h][f][e0+e']
                const int sg = tid >> 7, et = tid & 127;
                const int s0 = sg * 13 - (sg == 3 ? 1 : 0);  // 0,13,26,38 (row 38 dup, row 50 pad)
                const float* wq = Wq + h * (RP * RP) + e0 + et;
                float acc[13] = {};
                for (int f = 0; f < RP; ++f) {
                    const float w = wq[f * RP];
                    #pragma unroll
                    for (int i = 0; i < 13; ++i) acc[i] += Xs[s0 + i][f] * w;
                }
                #pragma unroll
                for (int i = 0; i < 13; ++i) Qc[s0 + i][et] = acc[i];
            }
            __syncthreads();
            for (int o = tid; o < HIS * HIS; o += 512) {
                const int s = o / HIS, t = o - s * HIS;
                float acc = (chunk == 0) ? 0.f : Sm[s][t];
                for (int e = 0; e < 128; ++e) acc += Qc[s][e] * Xs[t][e0 + e];
                Sm[s][t] = acc;
            }
        }
        __syncthreads();
        if (tid < HIS) {
            const int s = tid;
            float m = -1e30f;
            for (int t = 0; t < HIS; ++t) m = fmaxf(m, Sm[s][t]);
            m *= SCALEF;
            float sum = 0.f;
            for (int t = 0; t < HIS; ++t) { const float e = __expf(Sm[s][t] * SCALEF - m); Sm[s][t] = e; sum += e; }
            const float inv = 1.f / sum;
            for (int t = 0; t < HIS; ++t) Sm[s][t] *= inv;
        }
        for (int o = tid; o < HIS * VDIM; o += 512) {   // XVh = Xs * Wv[h]
            const int t = o >> 4, v = o & 15;
            const float* wp = Wv + h * (RP * VDIM) + v;
            float acc = 0.f;
            for (int f = 0; f < RP; ++f) acc += Xs[t][f] * wp[f * VDIM];
            XVh[t][v] = acc;
        }
        __syncthreads();
        for (int o = tid; o < HIS * VDIM; o += 512) {
            const int s = o >> 4, v = o & 15;
            float acc = 0.f;
            for (int t = 0; t < HIS; ++t) acc += Sm[s][t] * XVh[t][v];
            Vl[s][h * VDIM + v] = acc;
        }
    }
    __syncthreads();

    // additive pooling: wl[s] = SCALE * sum_q qv[q]*tanh(bk[q] + Vl[s]·Wk[:,q])
    {
        const int s = tid >> 3, g = tid & 7;
        float part = 0.f;
        if (s < HIS) {
            for (int q = g; q < QDIM; q += 8) {
                float acc = bk[q];
                const float* wp = Wk + q;
                for (int r = 0; r < RP; ++r) acc += Vl[s][r] * wp[r * QDIM];
                part += qv[q] * tanhf(acc);
            }
        }
        part += __shfl_down(part, 1, 64);
        part += __shfl_down(part, 2, 64);
        part += __shfl_down(part, 4, 64);
        if (g == 0 && s < HIS) wr[s] = part * SCALEF;
    }
    __syncthreads();
    if (tid == 0) {
        float m = -1e30f;
        for (int s = 0; s < HIS; ++s) m = fmaxf(m, wr[s]);
        float sum = 0.f;
        for (int s = 0; s < HIS; ++s) { const float e = __expf(wr[s] - m); wr[s] = e; sum += e; }
        const float inv = 1.f / sum;
        for (int s = 0; s < HIS; ++s) wr[s] *= inv;
    }
    __syncthreads();
    float* up = userR + b * RP;
    for (int r = tid; r < RP; r += 512) {
        float acc = 0.f;
        for (int s = 0; s < HIS; ++s) acc += wr[s] * Vl[s][r];
        up[r] = acc;
    }
}

// ---------------------------------------------------------------------------
// Scores: dot(cdd_repr, user_repr) + log_softmax over CDD. One wave per b.
// ---------------------------------------------------------------------------
__global__ __launch_bounds__(64)
void score_kernel(const float* __restrict__ cddR, const float* __restrict__ userR,
                  float* __restrict__ out)
{
    const int b = blockIdx.x;
    const int lane = threadIdx.x;
    const float* u = userR + b * RP;
    float sc[CDD];
    #pragma unroll
    for (int c = 0; c < CDD; ++c) {
        const float* cr = cddR + (b * CDD + c) * RP;
        float part = 0.f;
        for (int r = lane; r < RP; r += 64) part += cr[r] * u[r];
        #pragma unroll
        for (int off = 32; off > 0; off >>= 1) part += __shfl_down(part, off, 64);
        sc[c] = part;   // valid on lane 0
    }
    if (lane == 0) {
        float m = -1e30f;
        #pragma unroll
        for (int c = 0; c < CDD; ++c) m = fmaxf(m, sc[c]);
        float sum = 0.f;
        #pragma unroll
        for (int c = 0; c < CDD; ++c) sum += __expf(sc[c] - m);
        const float lse = m + logf(sum);
        #pragma unroll
        for (int c = 0; c < CDD; ++c) out[b * CDD + c] = sc[c] - lse;
    }
}

extern "C" void kernel_launch(void* const* d_in, const int* in_sizes, int n_in,
                              void* d_out, int out_size, void* d_ws, size_t ws_size,
                              hipStream_t stream) {
    const int*   cddT = (const int*)d_in[0];
    const int*   hisT = (const int*)d_in[1];
    const float* E    = (const float*)d_in[2];
    const float* Wq_w = (const float*)d_in[3];
    const float* Wv_w = (const float*)d_in[4];
    const float* Wk_w = (const float*)d_in[5];
    const float* bk_w = (const float*)d_in[6];
    const float* q_w  = (const float*)d_in[7];
    const float* Wq_n = (const float*)d_in[8];
    const float* Wv_n = (const float*)d_in[9];
    const float* Wk_n = (const float*)d_in[10];
    const float* bk_n = (const float*)d_in[11];
    const float* q_n  = (const float*)d_in[12];
    float* out = (float*)d_out;

    float* ws = (float*)d_ws;
    float* cdd_reprs = ws;                               // NB*CDD*RP = 327,680 f
    float* his_reprs = cdd_reprs + NB * CDD * RP;        // NB*HIS*RP = 3,276,800 f
    float* user_repr = his_reprs + NB * HIS * RP;        // NB*RP     = 65,536 f
    // total ws use: ~14.7 MB

    word_encoder_kernel<<<dim3(NB * NITEMS), dim3(512), 0, stream>>>(
        cddT, hisT, E, Wq_w, Wv_w, Wk_w, bk_w, q_w, cdd_reprs, his_reprs);
    user_encoder_kernel<<<dim3(NB), dim3(512), 0, stream>>>(
        his_reprs, Wq_n, Wv_n, Wk_n, bk_n, q_n, user_repr);
    score_kernel<<<dim3(NB), dim3(64), 0, stream>>>(cdd_reprs, user_repr, out);
}

// Round 2
// 5266.748 us; speedup vs baseline: 6.7786x; 6.7786x over previous
//
#include <hip/hip_runtime.h>
#include <hip/hip_bf16.h>
#include <math.h>

#define NB 256
#define CDD 5
#define HIS 50
#define NITEMS 55
#define TT 20
#define DD 300
#define NH 16
#define VDIM 16
#define RP 256
#define QDIM 200
#define SCALEF 0.057735026918962584f   // 1/sqrt(300)

typedef __attribute__((ext_vector_type(8))) short bf16x8;
typedef __attribute__((ext_vector_type(4))) short short4v;
typedef __attribute__((ext_vector_type(4))) float f32x4;

#define MFMA16(a, b, c) __builtin_amdgcn_mfma_f32_16x16x32_bf16((a), (b), (c), 0, 0, 0)

__device__ __forceinline__ ushort f2bf(float f) {
    union { float f; unsigned u; } c; c.f = f;
    unsigned u = c.u;
    return (ushort)((u + 0x7fffu + ((u >> 16) & 1u)) >> 16);
}
__device__ __forceinline__ float bf2f(ushort h) {
    union { unsigned u; float f; } c; c.u = ((unsigned)h) << 16;
    return c.f;
}

// LDS strides (elements)
#define XS  328   // Xbf / Qsm row stride (f/e dim padded to 320, +8 -> 656B rows, 16B-odd)
#define VS  264   // Vlbf row stride
#define XVS 96    // XVT row stride (token dim)

// ---------------------------------------------------------------------------
// Weight prep: transpose + bf16-quantize into K-contiguous layouts.
//   WqT[h][e(320)][f(320)]  (zeros for e>=300 or f>=300)
//   WvT[h*16+v][f(320)]     (zeros f>=300)
//   WkT[q(208)][r(256)]     (zeros q>=200)
// ---------------------------------------------------------------------------
__global__ __launch_bounds__(512)
void prep_weights(const float* __restrict__ Wq, const float* __restrict__ Wv,
                  const float* __restrict__ Wk,
                  ushort* __restrict__ WqT, ushort* __restrict__ WvT,
                  ushort* __restrict__ WkT)
{
    const int NQ = 16 * 320 * 320;
    const int NV = 256 * 320;
    const int NK = 208 * 256;
    for (int idx = blockIdx.x * 512 + threadIdx.x; idx < NQ + NV + NK;
         idx += gridDim.x * 512) {
        if (idx < NQ) {
            const int h = idx / 102400, rem = idx - h * 102400;
            const int e = rem / 320, k = rem - e * 320;
            const float v = (e < 300 && k < 300) ? Wq[(h * 300 + k) * 300 + e] : 0.f;
            WqT[idx] = f2bf(v);
        } else if (idx < NQ + NV) {
            const int j = idx - NQ;
            const int vg = j / 320, k = j - vg * 320;
            const int h = vg >> 4, vv = vg & 15;
            const float v = (k < 300) ? Wv[(h * 300 + k) * 16 + vv] : 0.f;
            WvT[j] = f2bf(v);
        } else {
            const int j = idx - NQ - NV;
            const int q = j / 256, r = j - q * 256;
            const float v = (q < 200) ? Wk[r * 200 + q] : 0.f;
            WkT[j] = f2bf(v);
        }
    }
}

// ---------------------------------------------------------------------------
// Q^T GEMM: D[e][s] = sum_f WqT[h][e][f] * X[s][f]. A=WqT (global), B=Xbf (LDS).
// Wave grid: we=0..3 (5 e-tiles each), ws=0..1 (s-tiles {0,1,2} / {3,4}).
// D written as Q row-major [s][e] (4 consecutive e per lane -> b64 store).
// ---------------------------------------------------------------------------
template<int NS>
__device__ __forceinline__ void q_gemm(const ushort* __restrict__ WqTh,
                                       const ushort* Xl, ushort* Ql,
                                       int we, int sbase, int l15, int lhi)
{
    f32x4 acc[5][NS];
#pragma unroll
    for (int m = 0; m < 5; ++m)
#pragma unroll
        for (int n = 0; n < NS; ++n) { f32x4 z = {0.f, 0.f, 0.f, 0.f}; acc[m][n] = z; }

#pragma unroll
    for (int ks = 0; ks < 10; ++ks) {
        const int off = ks * 32 + lhi * 8;
        bf16x8 B[NS];
#pragma unroll
        for (int n = 0; n < NS; ++n)
            B[n] = *(const bf16x8*)(Xl + ((sbase + n) * 16 + l15) * XS + off);
#pragma unroll
        for (int m = 0; m < 5; ++m) {
            const bf16x8 A = *(const bf16x8*)(WqTh + (80 * we + 16 * m + l15) * 320 + off);
#pragma unroll
            for (int n = 0; n < NS; ++n)
                acc[m][n] = MFMA16(A, B[n], acc[m][n]);
        }
    }
#pragma unroll
    for (int m = 0; m < 5; ++m)
#pragma unroll
        for (int n = 0; n < NS; ++n) {
            short4v p;
            p.x = (short)f2bf(acc[m][n][0]);
            p.y = (short)f2bf(acc[m][n][1]);
            p.z = (short)f2bf(acc[m][n][2]);
            p.w = (short)f2bf(acc[m][n][3]);
            const int srow = (sbase + n) * 16 + l15;
            const int ecol = 80 * we + 16 * m + lhi * 4;
            *(short4v*)(Ql + srow * XS + ecol) = p;
        }
}

// XV^T GEMM for one head-group g: D[v][t] = sum_f WvT[v][f] X[t][f].
__device__ __forceinline__ void xv_gemm(const ushort* __restrict__ WvTg,
                                        const ushort* Xl, ushort* XVTl,
                                        int w, int l15, int lhi)
{
    f32x4 acc[5];
#pragma unroll
    for (int n = 0; n < 5; ++n) { f32x4 z = {0.f, 0.f, 0.f, 0.f}; acc[n] = z; }
#pragma unroll
    for (int ks = 0; ks < 10; ++ks) {
        const int off = ks * 32 + lhi * 8;
        const bf16x8 A = *(const bf16x8*)(WvTg + (w * 16 + l15) * 320 + off);
#pragma unroll
        for (int n = 0; n < 5; ++n) {
            const bf16x8 B = *(const bf16x8*)(Xl + (n * 16 + l15) * XS + off);
            acc[n] = MFMA16(A, B, acc[n]);
        }
    }
#pragma unroll
    for (int n = 0; n < 5; ++n)
#pragma unroll
        for (int r = 0; r < 4; ++r)
            XVTl[(w * 16 + lhi * 4 + r) * XVS + n * 16 + l15] = f2bf(acc[n][r]);
}

// ---------------------------------------------------------------------------
// Word-level encoder (MFMA): 4 items per block, 512 threads (8 waves).
// ---------------------------------------------------------------------------
__global__ __launch_bounds__(512)
void word_encoder_mfma(const int* __restrict__ cddT, const int* __restrict__ hisT,
                       const float* __restrict__ E,
                       const ushort* __restrict__ WqT, const ushort* __restrict__ WvT,
                       const ushort* __restrict__ WkT,
                       const float* __restrict__ bk, const float* __restrict__ qv,
                       float* __restrict__ cddR, float* __restrict__ hisR)
{
    __shared__ ushort Xbf[92 * XS];    // 60,352 B  (rows 80..91 zero, cols >=300 zero)
    __shared__ ushort Qsm[92 * XS];    // 60,352 B  (later aliased as Vlbf[80][VS])
    __shared__ ushort XVT[128 * XVS];  // 24,576 B  per head-group XV^T
    __shared__ ushort At[4 * 32 * 32]; //  8,192 B  attn weights, A-frag layout
    __shared__ float  wrf[80];
    __shared__ int    toks[80];

    const int tid  = threadIdx.x;
    const int w    = tid >> 6;
    const int l15  = tid & 15;
    const int lhi  = (tid >> 4) & 3;

    // ---- phase 0: zero LDS, fetch token ids ----
    for (int i = tid; i < (92 * XS) / 2; i += 512) ((unsigned*)Xbf)[i] = 0u;
    for (int i = tid; i < (4 * 32 * 32) / 2; i += 512) ((unsigned*)At)[i] = 0u;
    if (tid < 80) {
        const int it_l = tid / 20, t = tid - it_l * 20;
        const int gi = blockIdx.x * 4 + it_l;
        const int b = gi / NITEMS, it = gi - b * NITEMS;
        toks[tid] = (it < CDD) ? cddT[(b * CDD + it) * TT + t]
                               : hisT[(b * HIS + (it - CDD)) * TT + t];
    }
    __syncthreads();

    // ---- phase 1: gather embeddings -> bf16 LDS ----
    for (int idx = tid; idx < 80 * 75; idx += 512) {
        const int row = idx / 75, q = idx - row * 75;
        const float4 v = ((const float4*)E)[toks[row] * 75 + q];
        short4v s;
        s.x = (short)f2bf(v.x); s.y = (short)f2bf(v.y);
        s.z = (short)f2bf(v.z); s.w = (short)f2bf(v.w);
        *(short4v*)(Xbf + row * XS + q * 4) = s;
    }

    // per-wave PV accumulators (Vl), one f32x4 per head
    f32x4 z4 = {0.f, 0.f, 0.f, 0.f};
    f32x4 vl0 = z4, vl1 = z4, vl2 = z4, vl3 = z4, vl4 = z4, vl5 = z4, vl6 = z4, vl7 = z4;
    f32x4 vl8 = z4, vl9 = z4, vl10 = z4, vl11 = z4, vl12 = z4, vl13 = z4, vl14 = z4, vl15 = z4;

    const int item = w >> 1;          // S/PV wave mapping
    const int mt   = w & 1;
    const int we   = w >> 1;          // Q-GEMM wave mapping
    const int ws   = w & 1;

    for (int g = 0; g < 2; ++g) {
        // zero XVT (incl. token cols >= 80)
        for (int i = tid; i < (128 * XVS) / 2; i += 512) ((unsigned*)XVT)[i] = 0u;
        __syncthreads();
        xv_gemm(WvT + g * 128 * 320, Xbf, XVT, w, l15, lhi);
        __syncthreads();

#pragma unroll 1
        for (int hh = 0; hh < 8; ++hh) {
            const int h = g * 8 + hh;
            const ushort* WqTh = WqT + h * 102400;

            // Q projection (all waves)
            if (ws == 0) q_gemm<3>(WqTh, Xbf, Qsm, we, 0, l15, lhi);
            else         q_gemm<2>(WqTh, Xbf, Qsm, we, 3, l15, lhi);
            __syncthreads();

            // S = Q X^T (per-wave: its item + row-half), in-register softmax
            {
                const ushort* qrow = Qsm + (20 * item + 16 * mt + l15) * XS;
                const ushort* x0   = Xbf + (20 * item + l15) * XS;
                const ushort* x1   = Xbf + (20 * item + 16 + l15) * XS;
                f32x4 a0 = z4, a1 = z4;
#pragma unroll
                for (int ks = 0; ks < 10; ++ks) {
                    const int off = ks * 32 + lhi * 8;
                    const bf16x8 qa = *(const bf16x8*)(qrow + off);
                    a0 = MFMA16(qa, *(const bf16x8*)(x0 + off), a0);
                    a1 = MFMA16(qa, *(const bf16x8*)(x1 + off), a1);
                }
                const bool c1 = (l15 < 4);
#pragma unroll
                for (int r = 0; r < 4; ++r) {
                    const float v0 = a0[r] * SCALEF;
                    const float v1 = c1 ? a1[r] * SCALEF : -1e30f;
                    float m = fmaxf(v0, v1);
                    m = fmaxf(m, __shfl_xor(m, 1, 64));
                    m = fmaxf(m, __shfl_xor(m, 2, 64));
                    m = fmaxf(m, __shfl_xor(m, 4, 64));
                    m = fmaxf(m, __shfl_xor(m, 8, 64));
                    float p0 = __expf(v0 - m);
                    float p1 = c1 ? __expf(v1 - m) : 0.f;
                    float s = p0 + p1;
                    s += __shfl_xor(s, 1, 64);
                    s += __shfl_xor(s, 2, 64);
                    s += __shfl_xor(s, 4, 64);
                    s += __shfl_xor(s, 8, 64);
                    const float inv = 1.f / s;
                    p0 *= inv; p1 *= inv;
                    const int sl = 16 * mt + lhi * 4 + r;
                    if (sl < 20) {
                        At[(item * 32 + sl) * 32 + l15] = f2bf(p0);
                        if (c1) At[(item * 32 + sl) * 32 + 16 + l15] = f2bf(p1);
                    }
                }
            }
            asm volatile("s_waitcnt lgkmcnt(0)" ::: "memory");

            // PV: one mfma, accumulate into per-head register Vl
            {
                const bf16x8 pa = *(const bf16x8*)(At + (item * 32 + 16 * mt + l15) * 32 + lhi * 8);
                const ushort* xvp = XVT + (hh * 16 + l15) * XVS + 20 * item + lhi * 8;
                union { bf16x8 v; short4v h4[2]; } bu;
                bu.h4[0] = *(const short4v*)xvp;
                bu.h4[1] = *(const short4v*)(xvp + 4);
#define VL_CASE(H) case H: vl##H = MFMA16(pa, bu.v, vl##H); break;
                switch (h) {
                    VL_CASE(0) VL_CASE(1) VL_CASE(2) VL_CASE(3)
                    VL_CASE(4) VL_CASE(5) VL_CASE(6) VL_CASE(7)
                    VL_CASE(8) VL_CASE(9) VL_CASE(10) VL_CASE(11)
                    VL_CASE(12) VL_CASE(13) VL_CASE(14) VL_CASE(15)
                }
#undef VL_CASE
            }
            __syncthreads();   // protects Qsm (next head) / At
        }
    }

    // ---- write Vl registers -> LDS (aliasing Qsm) ----
    ushort* Vlbf = Qsm;
#pragma unroll
    for (int r = 0; r < 4; ++r) {
        const int sl = 16 * mt + lhi * 4 + r;
        if (sl < 20) {
            ushort* vp = Vlbf + (20 * item + sl) * VS + l15;
#pragma unroll
            for (int h2 = 0; h2 < 16; ++h2) {
                float val = 0.f;
                switch (h2) {
                    case 0: val = vl0[r]; break;   case 1: val = vl1[r]; break;
                    case 2: val = vl2[r]; break;   case 3: val = vl3[r]; break;
                    case 4: val = vl4[r]; break;   case 5: val = vl5[r]; break;
                    case 6: val = vl6[r]; break;   case 7: val = vl7[r]; break;
                    case 8: val = vl8[r]; break;   case 9: val = vl9[r]; break;
                    case 10: val = vl10[r]; break; case 11: val = vl11[r]; break;
                    case 12: val = vl12[r]; break; case 13: val = vl13[r]; break;
                    case 14: val = vl14[r]; break; case 15: val = vl15[r]; break;
                }
                vp[h2 * 16] = f2bf(val);
            }
        }
    }
    if (tid < 80) wrf[tid] = 0.f;
    __syncthreads();

    // ---- keys GEMM + tanh + qv-dot (additive attention logits) ----
    for (int tile = w; tile < 65; tile += 8) {
        const int m = tile / 13, n = tile - m * 13;
        const int q = 16 * n + l15;
        const float bkq = (q < QDIM) ? bk[q] : 0.f;
        const float qvq = (q < QDIM) ? qv[q] : 0.f;
        f32x4 acc = z4;
#pragma unroll
        for (int ks = 0; ks < 8; ++ks) {
            const int off = ks * 32 + lhi * 8;
            const bf16x8 A = *(const bf16x8*)(Vlbf + (16 * m + l15) * VS + off);
            const bf16x8 B = *(const bf16x8*)(WkT + (16 * n + l15) * 256 + off);
            acc = MFMA16(A, B, acc);
        }
#pragma unroll
        for (int r = 0; r < 4; ++r) {
            float c = qvq * tanhf(acc[r] + bkq);
            c += __shfl_xor(c, 1, 64);
            c += __shfl_xor(c, 2, 64);
            c += __shfl_xor(c, 4, 64);
            c += __shfl_xor(c, 8, 64);
            if (l15 == 0) atomicAdd(&wrf[16 * m + lhi * 4 + r], c);
        }
    }
    __syncthreads();

    // ---- per-item softmax over tokens ----
    if (tid < 4) {
        const int i = tid;
        float m = -1e30f;
        for (int s = 0; s < 20; ++s) m = fmaxf(m, wrf[20 * i + s] * SCALEF);
        float sum = 0.f;
        for (int s = 0; s < 20; ++s) {
            const float e = __expf(wrf[20 * i + s] * SCALEF - m);
            wrf[20 * i + s] = e; sum += e;
        }
        const float inv = 1.f / sum;
        for (int s = 0; s < 20; ++s) wrf[20 * i + s] *= inv;
    }
    __syncthreads();

    // ---- pooled output ----
    for (int idx = tid; idx < 4 * 256; idx += 512) {
        const int i = idx >> 8, r = idx & 255;
        float s = 0.f;
#pragma unroll
        for (int t = 0; t < 20; ++t)
            s += wrf[20 * i + t] * bf2f(Vlbf[(20 * i + t) * VS + r]);
        const int gi = blockIdx.x * 4 + i;
        const int b = gi / NITEMS, it = gi - b * NITEMS;
        float* op = (it < CDD) ? (cddR + (b * CDD + it) * RP)
                               : (hisR + (b * HIS + (it - CDD)) * RP);
        op[r] = s;
    }
}

// ---------------------------------------------------------------------------
// User encoder (unchanged fp32 version from round 1)
// ---------------------------------------------------------------------------
#define FP2   257
#define CHW   129

__global__ __launch_bounds__(512)
void user_encoder_kernel(const float* __restrict__ hisR,
                         const float* __restrict__ Wq, const float* __restrict__ Wv,
                         const float* __restrict__ Wk, const float* __restrict__ bk,
                         const float* __restrict__ qv,
                         float* __restrict__ userR)
{
    __shared__ float Xs[HIS + 1][FP2];
    __shared__ float Vl[HIS][FP2];
    __shared__ float Qc[HIS + 1][CHW];
    __shared__ float Sm[HIS][HIS + 2];
    __shared__ float XVh[HIS][VDIM + 1];
    __shared__ float wr[HIS];

    const int tid = threadIdx.x;
    const int b = blockIdx.x;
    const float* xp = hisR + b * (HIS * RP);
    for (int i = tid; i < HIS * RP; i += 512) {
        const int s = i >> 8, f = i & 255;
        Xs[s][f] = xp[i];
    }
    __syncthreads();

    for (int h = 0; h < NH; ++h) {
        for (int chunk = 0; chunk < 2; ++chunk) {
            __syncthreads();
            const int e0 = chunk * 128;
            {
                const int sg = tid >> 7, et = tid & 127;
                const int s0 = sg * 13 - (sg == 3 ? 1 : 0);
                const float* wq = Wq + h * (RP * RP) + e0 + et;
                float acc[13] = {};
                for (int f = 0; f < RP; ++f) {
                    const float w = wq[f * RP];
#pragma unroll
                    for (int i = 0; i < 13; ++i) acc[i] += Xs[s0 + i][f] * w;
                }
#pragma unroll
                for (int i = 0; i < 13; ++i) Qc[s0 + i][et] = acc[i];
            }
            __syncthreads();
            for (int o = tid; o < HIS * HIS; o += 512) {
                const int s = o / HIS, t = o - s * HIS;
                float acc = (chunk == 0) ? 0.f : Sm[s][t];
                for (int e = 0; e < 128; ++e) acc += Qc[s][e] * Xs[t][e0 + e];
                Sm[s][t] = acc;
            }
        }
        __syncthreads();
        if (tid < HIS) {
            const int s = tid;
            float m = -1e30f;
            for (int t = 0; t < HIS; ++t) m = fmaxf(m, Sm[s][t]);
            m *= SCALEF;
            float sum = 0.f;
            for (int t = 0; t < HIS; ++t) { const float e = __expf(Sm[s][t] * SCALEF - m); Sm[s][t] = e; sum += e; }
            const float inv = 1.f / sum;
            for (int t = 0; t < HIS; ++t) Sm[s][t] *= inv;
        }
        for (int o = tid; o < HIS * VDIM; o += 512) {
            const int t = o >> 4, v = o & 15;
            const float* wp = Wv + h * (RP * VDIM) + v;
            float acc = 0.f;
            for (int f = 0; f < RP; ++f) acc += Xs[t][f] * wp[f * VDIM];
            XVh[t][v] = acc;
        }
        __syncthreads();
        for (int o = tid; o < HIS * VDIM; o += 512) {
            const int s = o >> 4, v = o & 15;
            float acc = 0.f;
            for (int t = 0; t < HIS; ++t) acc += Sm[s][t] * XVh[t][v];
            Vl[s][h * VDIM + v] = acc;
        }
    }
    __syncthreads();

    {
        const int s = tid >> 3, g = tid & 7;
        float part = 0.f;
        if (s < HIS) {
            for (int q = g; q < QDIM; q += 8) {
                float acc = bk[q];
                const float* wp = Wk + q;
                for (int r = 0; r < RP; ++r) acc += Vl[s][r] * wp[r * QDIM];
                part += qv[q] * tanhf(acc);
            }
        }
        part += __shfl_down(part, 1, 64);
        part += __shfl_down(part, 2, 64);
        part += __shfl_down(part, 4, 64);
        if (g == 0 && s < HIS) wr[s] = part * SCALEF;
    }
    __syncthreads();
    if (tid == 0) {
        float m = -1e30f;
        for (int s = 0; s < HIS; ++s) m = fmaxf(m, wr[s]);
        float sum = 0.f;
        for (int s = 0; s < HIS; ++s) { const float e = __expf(wr[s] - m); wr[s] = e; sum += e; }
        const float inv = 1.f / sum;
        for (int s = 0; s < HIS; ++s) wr[s] *= inv;
    }
    __syncthreads();
    float* up = userR + b * RP;
    for (int r = tid; r < RP; r += 512) {
        float acc = 0.f;
        for (int s = 0; s < HIS; ++s) acc += wr[s] * Vl[s][r];
        up[r] = acc;
    }
}

// ---------------------------------------------------------------------------
// Scores: dot + log_softmax
// ---------------------------------------------------------------------------
__global__ __launch_bounds__(64)
void score_kernel(const float* __restrict__ cddR, const float* __restrict__ userR,
                  float* __restrict__ out)
{
    const int b = blockIdx.x;
    const int lane = threadIdx.x;
    const float* u = userR + b * RP;
    float sc[CDD];
#pragma unroll
    for (int c = 0; c < CDD; ++c) {
        const float* cr = cddR + (b * CDD + c) * RP;
        float part = 0.f;
        for (int r = lane; r < RP; r += 64) part += cr[r] * u[r];
#pragma unroll
        for (int off = 32; off > 0; off >>= 1) part += __shfl_down(part, off, 64);
        sc[c] = part;
    }
    if (lane == 0) {
        float m = -1e30f;
#pragma unroll
        for (int c = 0; c < CDD; ++c) m = fmaxf(m, sc[c]);
        float sum = 0.f;
#pragma unroll
        for (int c = 0; c < CDD; ++c) sum += __expf(sc[c] - m);
        const float lse = m + logf(sum);
#pragma unroll
        for (int c = 0; c < CDD; ++c) out[b * CDD + c] = sc[c] - lse;
    }
}

extern "C" void kernel_launch(void* const* d_in, const int* in_sizes, int n_in,
                              void* d_out, int out_size, void* d_ws, size_t ws_size,
                              hipStream_t stream) {
    const int*   cddT = (const int*)d_in[0];
    const int*   hisT = (const int*)d_in[1];
    const float* E    = (const float*)d_in[2];
    const float* Wq_w = (const float*)d_in[3];
    const float* Wv_w = (const float*)d_in[4];
    const float* Wk_w = (const float*)d_in[5];
    const float* bk_w = (const float*)d_in[6];
    const float* q_w  = (const float*)d_in[7];
    const float* Wq_n = (const float*)d_in[8];
    const float* Wv_n = (const float*)d_in[9];
    const float* Wk_n = (const float*)d_in[10];
    const float* bk_n = (const float*)d_in[11];
    const float* q_n  = (const float*)d_in[12];
    float* out = (float*)d_out;

    char* wsb = (char*)d_ws;
    float*  cdd_reprs = (float*)(wsb);                    // 1,310,720 B
    float*  his_reprs = (float*)(wsb + 1310720);          // 13,107,200 B
    float*  user_repr = (float*)(wsb + 14417920);         // 262,144 B
    ushort* WqT       = (ushort*)(wsb + 14680064);        // 3,276,800 B
    ushort* WvT       = (ushort*)(wsb + 17956864);        // 163,840 B
    ushort* WkT       = (ushort*)(wsb + 18120704);        // 106,496 B

    prep_weights<<<dim3(2048), dim3(512), 0, stream>>>(Wq_w, Wv_w, Wk_w, WqT, WvT, WkT);
    word_encoder_mfma<<<dim3(NB * NITEMS / 4), dim3(512), 0, stream>>>(
        cddT, hisT, E, WqT, WvT, WkT, bk_w, q_w, cdd_reprs, his_reprs);
    user_encoder_kernel<<<dim3(NB), dim3(512), 0, stream>>>(
        his_reprs, Wq_n, Wv_n, Wk_n, bk_n, q_n, user_repr);
    score_kernel<<<dim3(NB), dim3(64), 0, stream>>>(cdd_reprs, user_repr, out);
}